// Round 3
// baseline (111.765 us; speedup 1.0000x reference)
//
#include <hip/hip_runtime.h>

namespace {

constexpr int B = 4, S = 4096, H = 16, D = 32;
constexpr int L = 32;             // chunk length
constexpr int NC = S / L;         // 128 chunks per sequence
constexpr int NBH = B * H;        // 64
constexpr int RS = H * D;         // 512 floats between consecutive time steps

__device__ __forceinline__ float fast_log2(float x) {
    return __builtin_amdgcn_logf(x);    // v_log_f32: log2(x)
}
__device__ __forceinline__ float fast_exp2(float x) {
    return __builtin_amdgcn_exp2f(x);   // v_exp_f32: 2^x
}

// ---------------- Kernel 1: per-chunk summaries ----------------
// W_j[m]  = v_j[m] * 2^{l_{L-1}[m] - l_j[m]}          (decay-to-end, in [0,1])
// KVb[bh][c][d][m] = sum_j k_j[d] * W_j[m]
// Gb[bh][c][m]     = 2^{l_{L-1}[m]}
__global__ __launch_bounds__(256)
void k1_chunk_summary(const float* __restrict__ Kp, const float* __restrict__ Vp,
                      const float* __restrict__ Gp, float* __restrict__ KVb,
                      float* __restrict__ Gb)
{
    __shared__ __align__(16) float k_s[L][D];
    __shared__ __align__(16) float w_s[L][D];
    __shared__ __align__(16) float l_s[L][D];

    const int blk = blockIdx.x;
    const int bh = blk / NC, c = blk % NC;
    const int b = bh / H, h = bh % H;
    const long base = ((long)b * S + (long)c * L) * RS + h * D;

    const int tid = threadIdx.x;
    const int i = tid >> 3;          // row within chunk (0..31)
    const int u = (tid & 7) * 4;     // quad offset within row (0..28)
    const long roff = base + (long)i * RS + u;

    float4 k4 = *(const float4*)(Kp + roff);
    float4 v4 = *(const float4*)(Vp + roff);
    float4 g4 = *(const float4*)(Gp + roff);
    *(float4*)&k_s[i][u] = k4;
    *(float4*)&w_s[i][u] = v4;
    *(float4*)&l_s[i][u] = g4;
    __syncthreads();

    // cumulative log2(gate) down each column m (monotone non-increasing)
    if (tid < D) {
        const int m = tid;
        float run = 0.f;
        #pragma unroll
        for (int t = 0; t < L; ++t) {
            run += fast_log2(fmaxf(l_s[t][m], 1e-37f));
            l_s[t][m] = run;
        }
    }
    __syncthreads();

    // W[j][m] = v * 2^{l_end - l_j}   (bounded: exponent <= 0)
    {
        float4 l4 = *(float4*)&l_s[i][u];
        float4 le = *(float4*)&l_s[L - 1][u];
        float4 w4 = *(float4*)&w_s[i][u];
        w4.x *= fast_exp2(le.x - l4.x);
        w4.y *= fast_exp2(le.y - l4.y);
        w4.z *= fast_exp2(le.z - l4.z);
        w4.w *= fast_exp2(le.w - l4.w);
        *(float4*)&w_s[i][u] = w4;
    }
    __syncthreads();

    // KV[d][m] = sum_j k[j][d] * W[j][m]
    const int d = tid >> 3;
    const int mg = (tid & 7) * 4;
    float a0 = 0.f, a1 = 0.f, a2 = 0.f, a3 = 0.f;
    #pragma unroll
    for (int j = 0; j < L; ++j) {
        float kv = k_s[j][d];
        float4 w = *(float4*)&w_s[j][mg];
        a0 += kv * w.x; a1 += kv * w.y; a2 += kv * w.z; a3 += kv * w.w;
    }
    const long ob = ((long)(bh * NC + c)) * (D * D) + d * D + mg;
    float4 o; o.x = a0; o.y = a1; o.z = a2; o.w = a3;
    *(float4*)(KVb + ob) = o;
    if (d == 0) {
        float4 lf = *(float4*)&l_s[L - 1][mg];
        float4 gg;
        gg.x = fast_exp2(lf.x); gg.y = fast_exp2(lf.y);
        gg.z = fast_exp2(lf.z); gg.w = fast_exp2(lf.w);
        *(float4*)(Gb + (long)(bh * NC + c) * D + mg) = gg;
    }
}

// ---------------- Kernel 2: inter-chunk scan (in-place KV -> S0) ----------------
// For each (bh, d, m): state_0 = 0; KVb[c] <- state_c; state_{c+1} = G_c*state_c + KV_c
__global__ __launch_bounds__(256)
void k2_scan(float* __restrict__ KVb, const float* __restrict__ Gb)
{
    const int bh = blockIdx.x >> 2;
    const int dg = blockIdx.x & 3;
    const int tid = threadIdx.x;
    const int dl = tid >> 5;           // 0..7
    const int m = tid & 31;
    const int d = dg * 8 + dl;

    const long kvoff = (long)bh * NC * (D * D) + d * D + m;
    const long goff = (long)bh * NC * D + m;

    float state = 0.f;
    float kv = KVb[kvoff];
    float g = Gb[goff];
    for (int c = 0; c < NC; ++c) {
        float kvn = 0.f, gn = 0.f;
        if (c + 1 < NC) {
            kvn = KVb[kvoff + (long)(c + 1) * (D * D)];
            gn = Gb[goff + (long)(c + 1) * D];
        }
        KVb[kvoff + (long)c * (D * D)] = state;   // chunk-START state
        state = g * state + kv;
        kv = kvn; g = gn;
    }
}

// ---------------- Kernel 3: per-chunk outputs ----------------
// out_i[m] = 2^{l_i[m]} * (q_i . S0[:,m])
//          + sum_{j<=i} (q_i.k_j) * v_j[m] * 2^{l_i[m]-l_j[m]}
__global__ __launch_bounds__(256)
void k3_out(const float* __restrict__ Qp, const float* __restrict__ Kp,
            const float* __restrict__ Vp, const float* __restrict__ Gp,
            const float* __restrict__ S0b, float* __restrict__ Op)
{
    __shared__ __align__(16) float q_s[L][D];
    __shared__ __align__(16) float kT[D][L + 1];
    __shared__ __align__(16) float w_s[L][D];
    __shared__ __align__(16) float l_s[L][D];
    __shared__ __align__(16) float s0_s[D][D];
    __shared__ __align__(16) float a_s[L][L + 1];

    const int blk = blockIdx.x;
    const int bh = blk / NC, c = blk % NC;
    const int b = bh / H, h = bh % H;
    const long base = ((long)b * S + (long)c * L) * RS + h * D;

    const int tid = threadIdx.x;
    const int i = tid >> 3;
    const int u = (tid & 7) * 4;
    const long roff = base + (long)i * RS + u;

    float4 q4 = *(const float4*)(Qp + roff);
    float4 k4 = *(const float4*)(Kp + roff);
    float4 v4 = *(const float4*)(Vp + roff);
    float4 g4 = *(const float4*)(Gp + roff);
    *(float4*)&q_s[i][u] = q4;
    kT[u + 0][i] = k4.x; kT[u + 1][i] = k4.y;
    kT[u + 2][i] = k4.z; kT[u + 3][i] = k4.w;
    *(float4*)&w_s[i][u] = v4;      // plain v (no pre-scale)
    *(float4*)&l_s[i][u] = g4;
    {
        const long s0off = (long)(bh * NC + c) * (D * D) + tid * 4;
        float4 s4 = *(const float4*)(S0b + s0off);
        *(float4*)&s0_s[tid >> 3][(tid & 7) * 4] = s4;
    }
    __syncthreads();

    if (tid < D) {
        const int m = tid;
        float run = 0.f;
        #pragma unroll
        for (int t = 0; t < L; ++t) {
            run += fast_log2(fmaxf(l_s[t][m], 1e-37f));
            l_s[t][m] = run;
        }
    }
    __syncthreads();

    // A[i][j] = q_i . k_j  (causal-masked, diag included)
    {
        const int j0 = (tid & 7) * 4;
        float a0 = 0.f, a1 = 0.f, a2 = 0.f, a3 = 0.f;
        #pragma unroll
        for (int d = 0; d < D; ++d) {
            float qv = q_s[i][d];
            a0 += qv * kT[d][j0 + 0];
            a1 += qv * kT[d][j0 + 1];
            a2 += qv * kT[d][j0 + 2];
            a3 += qv * kT[d][j0 + 3];
        }
        a_s[i][j0 + 0] = (j0 + 0 <= i) ? a0 : 0.f;
        a_s[i][j0 + 1] = (j0 + 1 <= i) ? a1 : 0.f;
        a_s[i][j0 + 2] = (j0 + 2 <= i) ? a2 : 0.f;
        a_s[i][j0 + 3] = (j0 + 3 <= i) ? a3 : 0.f;
    }
    __syncthreads();

    // out
    {
        const int mg = (tid & 7) * 4;
        const float4 li = *(float4*)&l_s[i][mg];

        // cross-chunk term: 2^{l_i} * (q_i . S0[:,m])
        float o0 = 0.f, o1 = 0.f, o2 = 0.f, o3 = 0.f;
        #pragma unroll
        for (int d = 0; d < D; ++d) {
            float qv = q_s[i][d];
            float4 s = *(float4*)&s0_s[d][mg];
            o0 += qv * s.x; o1 += qv * s.y; o2 += qv * s.z; o3 += qv * s.w;
        }
        o0 *= fast_exp2(li.x);
        o1 *= fast_exp2(li.y);
        o2 *= fast_exp2(li.z);
        o3 *= fast_exp2(li.w);

        // intra-chunk: sum_j A_ij * v_j * 2^{min(l_i - l_j, 0)}
        #pragma unroll
        for (int j = 0; j < L; ++j) {
            float av = a_s[i][j];
            float4 lj = *(float4*)&l_s[j][mg];
            float4 vj = *(float4*)&w_s[j][mg];
            o0 += av * vj.x * fast_exp2(fminf(li.x - lj.x, 0.f));
            o1 += av * vj.y * fast_exp2(fminf(li.y - lj.y, 0.f));
            o2 += av * vj.z * fast_exp2(fminf(li.z - lj.z, 0.f));
            o3 += av * vj.w * fast_exp2(fminf(li.w - lj.w, 0.f));
        }
        float4 r; r.x = o0; r.y = o1; r.z = o2; r.w = o3;
        *(float4*)(Op + base + (long)i * RS + mg) = r;
    }
}

} // namespace

extern "C" void kernel_launch(void* const* d_in, const int* in_sizes, int n_in,
                              void* d_out, int out_size, void* d_ws, size_t ws_size,
                              hipStream_t stream)
{
    const float* q = (const float*)d_in[0];
    const float* k = (const float*)d_in[1];
    const float* v = (const float*)d_in[2];
    const float* g = (const float*)d_in[3];
    float* out = (float*)d_out;

    float* KVb = (float*)d_ws;                       // [NBH][NC][D][D]  (33.55 MB)
    float* Gb = KVb + (long)NBH * NC * D * D;        // [NBH][NC][D]     (1.05 MB)

    dim3 blk(256);
    k1_chunk_summary<<<dim3(NBH * NC), blk, 0, stream>>>(k, v, g, KVb, Gb);
    k2_scan<<<dim3(NBH * 4), blk, 0, stream>>>(KVb, Gb);
    k3_out<<<dim3(NBH * NC), blk, 0, stream>>>(q, k, v, g, KVb, out);
}

// Round 4
// 88.886 us; speedup vs baseline: 1.2574x; 1.2574x over previous
//
#include <hip/hip_runtime.h>

namespace {

constexpr int B = 4, S = 4096, H = 16, D = 32;
constexpr int L = 32;             // chunk length
constexpr int NC = S / L;         // 128 chunks per sequence
constexpr int NBH = B * H;        // 64
constexpr int RS = H * D;         // 512 floats between consecutive time steps
constexpr int PW = 36;            // padded LDS row width (bank-conflict-free, 16B aligned)
constexpr float GEPS = 1.52587890625e-05f;  // 2^-16: per-step decay clamp
                                            // (7 steps * 16 = 112 < 126 -> no denormal
                                            //  cancellation in sub-block factorization)

__device__ __forceinline__ float flog2(float x) { return __builtin_amdgcn_logf(x); }
__device__ __forceinline__ float fexp2(float x) { return __builtin_amdgcn_exp2f(x); }

// ---------------- Kernel 1: per-chunk summaries ----------------
// l = cumsum log2(max(g,GEPS)) along rows (parallel prefix)
// W_j[m]  = v_j[m] * 2^{l_end[m] - l_j[m]}   (exponent <= 0)
// KVb[bh][c][d][m] = sum_j k_j[d] * W_j[m]
// Gb[bh][c][m]     = 2^{l_end[m]}
__global__ __launch_bounds__(256)
void k1_chunk_summary(const float* __restrict__ Kp, const float* __restrict__ Vp,
                      const float* __restrict__ Gp, float* __restrict__ KVb,
                      float* __restrict__ Gb)
{
    __shared__ float k_s[L][PW];
    __shared__ float w_s[L][PW];
    __shared__ float la[L][PW];
    __shared__ float lb[L][PW];
    __shared__ float e_row[D];

    const int blk = blockIdx.x;
    const int bh = blk / NC, c = blk % NC;
    const int b = bh / H, h = bh % H;
    const long base = ((long)b * S + (long)c * L) * RS + h * D;

    const int tid = threadIdx.x;
    const int i = tid >> 3;          // row 0..31
    const int u = (tid & 7) * 4;     // col quad 0..28
    const long roff = base + (long)i * RS + u;

    float4 k4 = *(const float4*)(Kp + roff);
    float4 v4 = *(const float4*)(Vp + roff);
    float4 g4 = *(const float4*)(Gp + roff);
    *(float4*)&k_s[i][u] = k4;

    float4 val;
    val.x = flog2(fmaxf(g4.x, GEPS));
    val.y = flog2(fmaxf(g4.y, GEPS));
    val.z = flog2(fmaxf(g4.z, GEPS));
    val.w = flog2(fmaxf(g4.w, GEPS));
    *(float4*)&la[i][u] = val;
    __syncthreads();
    // Hillis-Steele prefix along i (ping-pong la<->lb), result stays in regs
    { float4 t = {0,0,0,0}; if (i >= 1)  t = *(float4*)&la[i-1][u];
      val.x+=t.x; val.y+=t.y; val.z+=t.z; val.w+=t.w;
      *(float4*)&lb[i][u] = val; __syncthreads(); }
    { float4 t = {0,0,0,0}; if (i >= 2)  t = *(float4*)&lb[i-2][u];
      val.x+=t.x; val.y+=t.y; val.z+=t.z; val.w+=t.w;
      *(float4*)&la[i][u] = val; __syncthreads(); }
    { float4 t = {0,0,0,0}; if (i >= 4)  t = *(float4*)&la[i-4][u];
      val.x+=t.x; val.y+=t.y; val.z+=t.z; val.w+=t.w;
      *(float4*)&lb[i][u] = val; __syncthreads(); }
    { float4 t = {0,0,0,0}; if (i >= 8)  t = *(float4*)&lb[i-8][u];
      val.x+=t.x; val.y+=t.y; val.z+=t.z; val.w+=t.w;
      *(float4*)&la[i][u] = val; __syncthreads(); }
    { float4 t = {0,0,0,0}; if (i >= 16) t = *(float4*)&la[i-16][u];
      val.x+=t.x; val.y+=t.y; val.z+=t.z; val.w+=t.w; }  // no store needed

    if (i == L - 1) {
        *(float4*)&e_row[u] = val;
        float4 gg;
        gg.x = fexp2(val.x); gg.y = fexp2(val.y);
        gg.z = fexp2(val.z); gg.w = fexp2(val.w);
        *(float4*)(Gb + (long)(bh * NC + c) * D + u) = gg;
    }
    __syncthreads();

    {
        float4 e4 = *(float4*)&e_row[u];
        float4 w4;
        w4.x = v4.x * fexp2(e4.x - val.x);
        w4.y = v4.y * fexp2(e4.y - val.y);
        w4.z = v4.z * fexp2(e4.z - val.z);
        w4.w = v4.w * fexp2(e4.w - val.w);
        *(float4*)&w_s[i][u] = w4;
    }
    __syncthreads();

    // KV[d][m] = sum_j k[j][d] * W[j][m]
    const int d = tid >> 3;
    const int mg = (tid & 7) * 4;
    float4 acc = {0,0,0,0};
    #pragma unroll
    for (int j = 0; j < L; ++j) {
        float kv = k_s[j][d];
        float4 w = *(float4*)&w_s[j][mg];
        acc.x += kv * w.x; acc.y += kv * w.y; acc.z += kv * w.z; acc.w += kv * w.w;
    }
    *(float4*)(KVb + (long)(bh * NC + c) * (D * D) + d * D + mg) = acc;
}

// ---------------- Kernel 2: inter-chunk scan (in-place KV -> S0) ----------------
__global__ __launch_bounds__(256)
void k2_scan(float* __restrict__ KVb, const float* __restrict__ Gb)
{
    const int bh = blockIdx.x >> 2;
    const int dg = blockIdx.x & 3;
    const int tid = threadIdx.x;
    const int dl = tid >> 5;
    const int m = tid & 31;
    const int d = dg * 8 + dl;

    const long kvoff = (long)bh * NC * (D * D) + d * D + m;
    const long goff = (long)bh * NC * D + m;

    float state = 0.f;
    float kv = KVb[kvoff];
    float g = Gb[goff];
    for (int c = 0; c < NC; ++c) {
        float kvn = 0.f, gn = 0.f;
        if (c + 1 < NC) {
            kvn = KVb[kvoff + (long)(c + 1) * (D * D)];
            gn = Gb[goff + (long)(c + 1) * D];
        }
        KVb[kvoff + (long)c * (D * D)] = state;   // chunk-START state
        state = g * state + kv;
        kv = kvn; g = gn;
    }
}

// ---------------- Kernel 3: per-chunk outputs ----------------
// out_i[m] = 2^{l_i[m]} * (q_i . S0[:,m])
//          + sum_{s<=si} 2^{l_i[m]-e_s[m]} * sum_{j in s, j<=i} A_ij * W_j[m]
// where W_j[m] = v_j[m]*2^{e_{s(j)}[m]-l_j[m]}, e_s = l at end of sub-block s (8 rows).
__global__ __launch_bounds__(256)
void k3_out(const float* __restrict__ Qp, const float* __restrict__ Kp,
            const float* __restrict__ Vp, const float* __restrict__ Gp,
            const float* __restrict__ S0b, float* __restrict__ Op)
{
    __shared__ float q_s[L][PW];
    __shared__ float kT[D][L + 1];
    __shared__ float w_s[L][PW];
    __shared__ float la[L][PW];
    __shared__ float lb[L][PW];     // prefix scratch, then reused for S0
    __shared__ float a_s[L][L + 1];
    __shared__ float es[4][D];      // sub-block end l

    const int blk = blockIdx.x;
    const int bh = blk / NC, c = blk % NC;
    const int b = bh / H, h = bh % H;
    const long base = ((long)b * S + (long)c * L) * RS + h * D;

    const int tid = threadIdx.x;
    const int i = tid >> 3;
    const int u = (tid & 7) * 4;
    const int si = i >> 3;           // sub-block id == wave id (uniform per wave)
    const long roff = base + (long)i * RS + u;

    float4 q4 = *(const float4*)(Qp + roff);
    float4 k4 = *(const float4*)(Kp + roff);
    float4 v4 = *(const float4*)(Vp + roff);
    float4 g4 = *(const float4*)(Gp + roff);
    float4 s04 = *(const float4*)(S0b + (long)(bh * NC + c) * (D * D) + tid * 4);

    *(float4*)&q_s[i][u] = q4;
    kT[u + 0][i] = k4.x; kT[u + 1][i] = k4.y;
    kT[u + 2][i] = k4.z; kT[u + 3][i] = k4.w;

    float4 val;
    val.x = flog2(fmaxf(g4.x, GEPS));
    val.y = flog2(fmaxf(g4.y, GEPS));
    val.z = flog2(fmaxf(g4.z, GEPS));
    val.w = flog2(fmaxf(g4.w, GEPS));
    *(float4*)&la[i][u] = val;
    __syncthreads();
    { float4 t = {0,0,0,0}; if (i >= 1)  t = *(float4*)&la[i-1][u];
      val.x+=t.x; val.y+=t.y; val.z+=t.z; val.w+=t.w;
      *(float4*)&lb[i][u] = val; __syncthreads(); }
    { float4 t = {0,0,0,0}; if (i >= 2)  t = *(float4*)&lb[i-2][u];
      val.x+=t.x; val.y+=t.y; val.z+=t.z; val.w+=t.w;
      *(float4*)&la[i][u] = val; __syncthreads(); }
    { float4 t = {0,0,0,0}; if (i >= 4)  t = *(float4*)&la[i-4][u];
      val.x+=t.x; val.y+=t.y; val.z+=t.z; val.w+=t.w;
      *(float4*)&lb[i][u] = val; __syncthreads(); }
    { float4 t = {0,0,0,0}; if (i >= 8)  t = *(float4*)&lb[i-8][u];
      val.x+=t.x; val.y+=t.y; val.z+=t.z; val.w+=t.w;
      *(float4*)&la[i][u] = val; __syncthreads(); }
    { float4 t = {0,0,0,0}; if (i >= 16) t = *(float4*)&la[i-16][u];
      val.x+=t.x; val.y+=t.y; val.z+=t.z; val.w+=t.w; }  // final l_i in regs

    // sub-block end rows publish e_s; lb is free now -> stash S0 there
    if ((i & 7) == 7) *(float4*)&es[si][u] = val;
    *(float4*)&lb[tid >> 3][(tid & 7) * 4] = s04;
    __syncthreads();

    // W_j = v_j * 2^{e_{s(j)} - l_j}   (exponent <= 0)
    {
        float4 e4 = *(float4*)&es[si][u];
        float4 w4;
        w4.x = v4.x * fexp2(e4.x - val.x);
        w4.y = v4.y * fexp2(e4.y - val.y);
        w4.z = v4.z * fexp2(e4.z - val.z);
        w4.w = v4.w * fexp2(e4.w - val.w);
        *(float4*)&w_s[i][u] = w4;
    }

    // preload own q row to registers (reused by A and S0 loops)
    float4 tq[8];
    #pragma unroll
    for (int dd = 0; dd < 8; ++dd) tq[dd] = *(float4*)&q_s[i][dd * 4];

    // A[i][j0..j0+3] = q_i . k_j  (unmasked; consumers only use j <= i)
    {
        const int j0 = u;
        float4 a = {0,0,0,0};
        #pragma unroll
        for (int dd = 0; dd < 8; ++dd) {
            #pragma unroll
            for (int cc = 0; cc < 4; ++cc) {
                const float qv = (&tq[dd].x)[cc];
                const int d = dd * 4 + cc;
                a.x += qv * kT[d][j0 + 0];
                a.y += qv * kT[d][j0 + 1];
                a.z += qv * kT[d][j0 + 2];
                a.w += qv * kT[d][j0 + 3];
            }
        }
        a_s[i][j0 + 0] = a.x; a_s[i][j0 + 1] = a.y;
        a_s[i][j0 + 2] = a.z; a_s[i][j0 + 3] = a.w;
    }
    __syncthreads();

    // cross-chunk term: 2^{l_i} * (q_i . S0[:,m])
    float4 o = {0,0,0,0};
    #pragma unroll
    for (int dd = 0; dd < 8; ++dd) {
        #pragma unroll
        for (int cc = 0; cc < 4; ++cc) {
            const float qv = (&tq[dd].x)[cc];
            float4 s4 = *(float4*)&lb[dd * 4 + cc][u];
            o.x += qv * s4.x; o.y += qv * s4.y; o.z += qv * s4.z; o.w += qv * s4.w;
        }
    }
    o.x *= fexp2(val.x); o.y *= fexp2(val.y);
    o.z *= fexp2(val.z); o.w *= fexp2(val.w);

    // intra-chunk: sub-block factorized
    for (int s = 0; s <= si; ++s) {
        float4 t = {0,0,0,0};
        const int jb = s << 3;
        if (s < si) {
            #pragma unroll
            for (int jj = 0; jj < 8; ++jj) {
                const float av = a_s[i][jb + jj];
                float4 w = *(float4*)&w_s[jb + jj][u];
                t.x += av * w.x; t.y += av * w.y; t.z += av * w.z; t.w += av * w.w;
            }
        } else {
            #pragma unroll
            for (int jj = 0; jj < 8; ++jj) {
                const int j = jb + jj;
                const float av = (j <= i) ? a_s[i][j] : 0.f;
                float4 w = *(float4*)&w_s[j][u];
                t.x += av * w.x; t.y += av * w.y; t.z += av * w.z; t.w += av * w.w;
            }
        }
        float4 e4 = *(float4*)&es[s][u];
        o.x += fexp2(val.x - e4.x) * t.x;
        o.y += fexp2(val.y - e4.y) * t.y;
        o.z += fexp2(val.z - e4.z) * t.z;
        o.w += fexp2(val.w - e4.w) * t.w;
    }

    *(float4*)(Op + roff) = o;
}

} // namespace

extern "C" void kernel_launch(void* const* d_in, const int* in_sizes, int n_in,
                              void* d_out, int out_size, void* d_ws, size_t ws_size,
                              hipStream_t stream)
{
    const float* q = (const float*)d_in[0];
    const float* k = (const float*)d_in[1];
    const float* v = (const float*)d_in[2];
    const float* g = (const float*)d_in[3];
    float* out = (float*)d_out;

    float* KVb = (float*)d_ws;                       // [NBH][NC][D][D]  (33.55 MB)
    float* Gb = KVb + (long)NBH * NC * D * D;        // [NBH][NC][D]     (1.05 MB)

    dim3 blk(256);
    k1_chunk_summary<<<dim3(NBH * NC), blk, 0, stream>>>(k, v, g, KVb, Gb);
    k2_scan<<<dim3(NBH * 4), blk, 0, stream>>>(KVb, Gb);
    k3_out<<<dim3(NBH * NC), blk, 0, stream>>>(q, k, v, g, KVb, out);
}